// Round 10
// baseline (228.134 us; speedup 1.0000x reference)
//
#include <hip/hip_runtime.h>
#include <hip/hip_bf16.h>

#define N_NODES 8192
#define DIN     512
#define DOUT    256
#define ALPHA   0.2f
#define LOG2E   1.4426950408889634f

typedef __bf16 bf16x8 __attribute__((ext_vector_type(8)));
typedef __bf16 bf16x4 __attribute__((ext_vector_type(4)));
typedef float  f32x4  __attribute__((ext_vector_type(4)));
typedef int    i32x4  __attribute__((ext_vector_type(4)));
typedef unsigned u32x4 __attribute__((ext_vector_type(4)));

#define MFMA16 __builtin_amdgcn_mfma_f32_16x16x32_bf16

// ---------------------------------------------------------------------------
// A0: repack weight f32 [512][256] -> wB bf16 fragment layout. Zeroes kmaxkey.
__global__ __launch_bounds__(256) void k_repack_w(const float* __restrict__ w,
                                                  bf16x8* __restrict__ wB,
                                                  unsigned* __restrict__ kmaxkey) {
    if (blockIdx.x == 0 && threadIdx.x == 0) *kmaxkey = 0u;
    int u = blockIdx.x * 256 + threadIdx.x;   // 16384 units
    int lane = u & 63, t = u >> 6;
    int nt = t & 15, kt = t >> 4;
    int k0 = kt * 32 + (lane >> 4) * 8;
    int col = nt * 16 + (lane & 15);
    bf16x8 r;
#pragma unroll
    for (int i = 0; i < 8; ++i) r[i] = (__bf16)w[(size_t)(k0 + i) * DOUT + col];
    wB[u] = r;
}

// ---------------------------------------------------------------------------
// A1 (fused): v = node @ weight in registers; emits vB fragments (LDS bounce),
// Q/K scalars, global K-max.
__global__ __launch_bounds__(256) void k_gemm1f(const float* __restrict__ node,
                                                const bf16x8* __restrict__ wB,
                                                const float* __restrict__ a,
                                                bf16x8* __restrict__ vBo,
                                                float* __restrict__ Q, float* __restrict__ K,
                                                unsigned* __restrict__ kmaxkey) {
    __shared__ __bf16 vsh[32][260];   // +4 pad
    __shared__ float qksh[32][2];
    int lane = threadIdx.x & 63, w = threadIdx.x >> 6;
    int r15 = lane & 15, g = lane >> 4;
    int nh = w & 1, rh = w >> 1;
    int rowbase = blockIdx.x * 32;
    int myrow = rowbase + rh * 16 + r15;
    const float* np = node + (size_t)myrow * DIN + g * 8;

    f32x4 acc[8];
#pragma unroll
    for (int j = 0; j < 8; ++j) acc[j] = (f32x4){0.f, 0.f, 0.f, 0.f};

    f32x4 c0 = *(const f32x4*)np;
    f32x4 c1 = *(const f32x4*)(np + 4);
    f32x4 c2 = *(const f32x4*)(np + 32);
    f32x4 c3 = *(const f32x4*)(np + 36);
    const bf16x8* wp = wB + (size_t)(nh * 8) * 64 + lane;
    bf16x8 fr0 = wp[0], fr1 = wp[64], fr2 = wp[128], fr3 = wp[192];
    bf16x8 fr4 = wp[256], fr5 = wp[320], fr6 = wp[384], fr7 = wp[448];

    for (int kt = 0; kt < 16; ++kt) {
        f32x4 u0 = c0, u1 = c1;
        c0 = c2; c1 = c3;
        if (kt + 2 < 16) {
            c2 = *(const f32x4*)(np + (kt + 2) * 32);
            c3 = *(const f32x4*)(np + (kt + 2) * 32 + 4);
        }
        bf16x8 f0 = fr0, f1 = fr1, f2 = fr2, f3 = fr3;
        bf16x8 f4 = fr4, f5 = fr5, f6 = fr6, f7 = fr7;
        if (kt + 1 < 16) {
            const bf16x8* wn = wB + ((size_t)(kt + 1) * 16 + nh * 8) * 64 + lane;
            fr0 = wn[0]; fr1 = wn[64]; fr2 = wn[128]; fr3 = wn[192];
            fr4 = wn[256]; fr5 = wn[320]; fr6 = wn[384]; fr7 = wn[448];
        }
        bf16x8 af;
#pragma unroll
        for (int i = 0; i < 4; ++i) { af[i] = (__bf16)u0[i]; af[i + 4] = (__bf16)u1[i]; }
        acc[0] = MFMA16(af, f0, acc[0], 0, 0, 0);
        acc[1] = MFMA16(af, f1, acc[1], 0, 0, 0);
        acc[2] = MFMA16(af, f2, acc[2], 0, 0, 0);
        acc[3] = MFMA16(af, f3, acc[3], 0, 0, 0);
        acc[4] = MFMA16(af, f4, acc[4], 0, 0, 0);
        acc[5] = MFMA16(af, f5, acc[5], 0, 0, 0);
        acc[6] = MFMA16(af, f6, acc[6], 0, 0, 0);
        acc[7] = MFMA16(af, f7, acc[7], 0, 0, 0);
    }

    float qp0 = 0.f, qp1 = 0.f, qp2 = 0.f, qp3 = 0.f;
    float kp0 = 0.f, kp1 = 0.f, kp2 = 0.f, kp3 = 0.f;
#pragma unroll
    for (int j = 0; j < 8; ++j) {
        int col = (nh * 8 + j) * 16 + r15;
        float a1 = a[col], a2 = a[DOUT + col];
        qp0 += acc[j][0] * a1; qp1 += acc[j][1] * a1;
        qp2 += acc[j][2] * a1; qp3 += acc[j][3] * a1;
        kp0 += acc[j][0] * a2; kp1 += acc[j][1] * a2;
        kp2 += acc[j][2] * a2; kp3 += acc[j][3] * a2;
    }
#pragma unroll
    for (int m = 1; m < 16; m <<= 1) {
        qp0 += __shfl_xor(qp0, m); qp1 += __shfl_xor(qp1, m);
        qp2 += __shfl_xor(qp2, m); qp3 += __shfl_xor(qp3, m);
        kp0 += __shfl_xor(kp0, m); kp1 += __shfl_xor(kp1, m);
        kp2 += __shfl_xor(kp2, m); kp3 += __shfl_xor(kp3, m);
    }

#pragma unroll
    for (int j = 0; j < 8; ++j)
#pragma unroll
        for (int r = 0; r < 4; ++r)
            vsh[rh * 16 + g * 4 + r][(nh * 8 + j) * 16 + r15] = (__bf16)acc[j][r];
    if (nh == 0 && r15 == 0) {
        int rl = rh * 16 + g * 4;
        qksh[rl + 0][0] = qp0; qksh[rl + 1][0] = qp1; qksh[rl + 2][0] = qp2; qksh[rl + 3][0] = qp3;
        qksh[rl + 0][1] = kp0; qksh[rl + 1][1] = kp1; qksh[rl + 2][1] = kp2; qksh[rl + 3][1] = kp3;
    }
    __syncthreads();
    if (nh == 1 && r15 == 0) {
        int rl = rh * 16 + g * 4;
        int rw = rowbase + rl;
        float q0 = qp0 + qksh[rl + 0][0], q1 = qp1 + qksh[rl + 1][0];
        float q2 = qp2 + qksh[rl + 2][0], q3 = qp3 + qksh[rl + 3][0];
        float k0 = kp0 + qksh[rl + 0][1], k1 = kp1 + qksh[rl + 1][1];
        float k2 = kp2 + qksh[rl + 2][1], k3 = kp3 + qksh[rl + 3][1];
        Q[rw + 0] = q0; Q[rw + 1] = q1; Q[rw + 2] = q2; Q[rw + 3] = q3;
        K[rw + 0] = k0; K[rw + 1] = k1; K[rw + 2] = k2; K[rw + 3] = k3;
        float km = fmaxf(fmaxf(k0, k1), fmaxf(k2, k3));
        unsigned bits = __float_as_uint(km);
        unsigned key = (bits & 0x80000000u) ? ~bits : (bits | 0x80000000u);
        atomicMax(kmaxkey, key);
    }
#pragma unroll
    for (int uu = 0; uu < 4; ++uu) {
        int nt = w * 4 + uu;
        bf16x8 t;
#pragma unroll
        for (int i = 0; i < 8; ++i) t[i] = vsh[g * 8 + i][nt * 16 + r15];
        vBo[((size_t)blockIdx.x * 16 + nt) * 64 + lane] = t;
    }
}

// ---------------------------------------------------------------------------
// B (round-10): r3 pipeline on a REGISTER DIET for 3 waves/SIMD.
// r9 counters: all pipes <35% busy, occupancy 21% (2 waves/SIMD), ~46 MB
// scratch spill, runtime insensitive to HBM traffic -> latency-bound with
// too few resident waves. Diet: (1) vB single-buffered, frags for step t+1
// loaded at the TAIL of step t (consumed after the next barrier = full-step
// latency cover; 16 VGPR, was 32 dual-set); (2) adj ring shrunk to ONE
// 4-load chunk (16 VGPR, was 32) on a 2-step cadence: pack+reissue at
// after-step0 (halfB of G+1, then issue halfA of G+2) and after-step2
// (pack halfA of G+2, issue halfB of G+2); each chunk in flight 2 steps
// (~1700cy >> HBM 900cy). Un mask prefetch moves to after-step1 (one full
// barrier after the last contributing pack -- fencing preserved).
// launch_bounds(256,3) pins the unified VGPR budget to ~170 (live ~155).
template<int JS>
__global__ __launch_bounds__(256, 3) void k_attn(const int* __restrict__ adj,
                                                 const bf16x8* __restrict__ vBg,
                                                 const float* __restrict__ Q,
                                                 const float* __restrict__ K,
                                                 const unsigned* __restrict__ kmaxkey,
                                                 __bf16* __restrict__ accB,
                                                 float* __restrict__ Sp) {
    constexpr int JR   = N_NODES / JS;
    constexpr int BIT  = JR / 32;          // k-steps (32 for JS=8)
    constexpr int NG   = BIT / 4;          // 4-step groups
    constexpr int MSTR = BIT + 4;          // pad
    __shared__ float    Ks[JR];
    __shared__ unsigned Ms[64][MSTR];
    __shared__ bf16x8   pT[2][4][64];

    int bid = blockIdx.x;
    int rb = bid / JS, p = bid % JS;       // p == XCD id (grid % 8 == 0)
    int lane = threadIdx.x & 63, w = threadIdx.x >> 6;
    int r15 = lane & 15, g = lane >> 4;
    int rowbase = rb * 64;
    int prow = rowbase + w * 16 + r15;
    int j0 = p * JR;

    const int hrow = w * 2 + (lane >> 5);          // 0..7
    const int* abase = adj + (size_t)(rowbase + hrow) * N_NODES + j0 + (lane & 31) * 4;

    // chunk = 4 loads (rows (H*4+q)*8 + hrow, q=0..3) of group GG's 128-col span
#define ISSUE4(L, GG, H) { _Pragma("unroll")                                     \
    for (int q = 0; q < 4; ++q)                                                  \
        L[q] = *(const i32x4*)(abase + (size_t)(((H) * 4 + q) * 8) * N_NODES + (GG) * 128); }

#define PACK4(L, GG, H) { _Pragma("unroll") for (int q = 0; q < 4; ++q) {        \
    unsigned long long b0_ = __ballot(L[q][0] != 0);                             \
    unsigned long long b1_ = __ballot(L[q][1] != 0);                             \
    unsigned long long b2_ = __ballot(L[q][2] != 0);                             \
    unsigned long long b3_ = __ballot(L[q][3] != 0);                             \
    if ((lane & 31) == 0) {                                                      \
        int hi_ = lane >> 5;                                                     \
        u32x4 u_;                                                                \
        u_[0] = hi_ ? (unsigned)(b0_ >> 32) : (unsigned)b0_;                     \
        u_[1] = hi_ ? (unsigned)(b1_ >> 32) : (unsigned)b1_;                     \
        u_[2] = hi_ ? (unsigned)(b2_ >> 32) : (unsigned)b2_;                     \
        u_[3] = hi_ ? (unsigned)(b3_ >> 32) : (unsigned)b3_;                     \
        *(u32x4*)&Ms[((H) * 4 + q) * 8 + hrow][(GG) * 4] = u_;                   \
    } } }

    // ---- prologue: pack group0 (both halves) + group1 halfA; issue g1 halfB
    i32x4 La[4];
    ISSUE4(La, 0, 0)
    for (int s = threadIdx.x * 4; s < JR; s += 1024)
        *(f32x4*)&Ks[s] = *(const f32x4*)&K[j0 + s];
    PACK4(La, 0, 0)
    ISSUE4(La, 0, 1)

    float qi = Q[prow];
    unsigned kk = *kmaxkey;
    unsigned kb = (kk & 0x80000000u) ? (kk ^ 0x80000000u) : ~kk;
    float kmax = __uint_as_float(kb);
    float t0 = qi + kmax;
    float c2 = fmaxf(t0, ALPHA * t0) * LOG2E;
    float qiL = qi * LOG2E;
    float A1 = qiL - c2;
    float A2 = ALPHA * qiL - c2;

    PACK4(La, 0, 1)
    ISSUE4(La, 1, 0)

    const bf16x8* vbp = vBg + ((size_t)(p * BIT) * 16 + w * 4) * 64 + lane;

    f32x4 acc[4][4];
#pragma unroll
    for (int m = 0; m < 4; ++m)
#pragma unroll
        for (int n = 0; n < 4; ++n) acc[m][n] = (f32x4){0.f, 0.f, 0.f, 0.f};
    float sl = 0.f;

    PACK4(La, 1, 0)
    ISSUE4(La, 1, 1)       // in flight; packed at after-step0 of G=0

    // vB single-buffer: step-0 fragments
    bf16x8 bC0 = vbp[0], bC1 = vbp[64], bC2 = vbp[128], bC3 = vbp[192];

    // Ks + Ms(group0 + group1-halfA) visible; g1-halfB loads + bC in flight.
    asm volatile("s_waitcnt lgkmcnt(0)" ::: "memory");
    __builtin_amdgcn_s_barrier();
    asm volatile("" ::: "memory");

    u32x4 Uc = *(const u32x4*)&Ms[w * 16 + r15][0];
    u32x4 Un = Uc;

#define EXPBLK(WN4, SN, kstep)                                                  \
    {                                                                           \
        f32x4 q0 = *(const f32x4*)&Ks[(kstep) * 32 + g * 8];                    \
        f32x4 q1 = *(const f32x4*)&Ks[(kstep) * 32 + g * 8 + 4];                \
        unsigned bsh = (SN) * 8 + g * 2;                                        \
        unsigned m0 = (WN4)[0] >> bsh, m1 = (WN4)[1] >> bsh;                    \
        unsigned m2 = (WN4)[2] >> bsh, m3 = (WN4)[3] >> bsh;                    \
        _Pragma("unroll")                                                       \
        for (int i = 0; i < 8; ++i) {                                           \
            float kj = (i < 4) ? q0[i] : q1[i - 4];                             \
            float f1 = __builtin_fmaf(kj, LOG2E, A1);                           \
            float f2 = __builtin_fmaf(kj, ALPHA * LOG2E, A2);                   \
            float pv = __builtin_amdgcn_exp2f(fmaxf(f1, f2));                   \
            unsigned mm_ = (i & 3) == 0 ? m0 : ((i & 3) == 1 ? m1 : ((i & 3) == 2 ? m2 : m3)); \
            pv = (mm_ & (1u << (i >> 2))) ? pv : 0.f;                           \
            sl += pv;                                                           \
            afc[i] = (__bf16)pv;                                                \
        }                                                                       \
    }

    bf16x8 afc;
    EXPBLK(Uc, 0, 0)

    // step body: store af(t) -> barrier -> pa reads -> exp(t+1) -> 16 MFMA
    // with bC (loaded at tail of step t-1) -> tail-load bC for t+1.
#define BODYM(WN4, SN, BUF, itv)                                                \
    {                                                                           \
        pT[BUF][w][lane] = afc;                                                 \
        asm volatile("s_waitcnt lgkmcnt(0)" ::: "memory");                      \
        __builtin_amdgcn_s_barrier();                                           \
        asm volatile("" ::: "memory");                                         \
        bf16x8 pa0 = pT[BUF][0][lane], pa1 = pT[BUF][1][lane];                  \
        bf16x8 pa2 = pT[BUF][2][lane], pa3 = pT[BUF][3][lane];                  \
        if ((itv) + 1 < BIT) EXPBLK(WN4, SN, (itv) + 1)                         \
        acc[0][0] = MFMA16(pa0, bC0, acc[0][0], 0, 0, 0);                       \
        acc[0][1] = MFMA16(pa0, bC1, acc[0][1], 0, 0, 0);                       \
        acc[0][2] = MFMA16(pa0, bC2, acc[0][2], 0, 0, 0);                       \
        acc[0][3] = MFMA16(pa0, bC3, acc[0][3], 0, 0, 0);                       \
        acc[1][0] = MFMA16(pa1, bC0, acc[1][0], 0, 0, 0);                       \
        acc[1][1] = MFMA16(pa1, bC1, acc[1][1], 0, 0, 0);                       \
        acc[1][2] = MFMA16(pa1, bC2, acc[1][2], 0, 0, 0);                       \
        acc[1][3] = MFMA16(pa1, bC3, acc[1][3], 0, 0, 0);                       \
        acc[2][0] = MFMA16(pa2, bC0, acc[2][0], 0, 0, 0);                       \
        acc[2][1] = MFMA16(pa2, bC1, acc[2][1], 0, 0, 0);                       \
        acc[2][2] = MFMA16(pa2, bC2, acc[2][2], 0, 0, 0);                       \
        acc[2][3] = MFMA16(pa2, bC3, acc[2][3], 0, 0, 0);                       \
        acc[3][0] = MFMA16(pa3, bC0, acc[3][0], 0, 0, 0);                       \
        acc[3][1] = MFMA16(pa3, bC1, acc[3][1], 0, 0, 0);                       \
        acc[3][2] = MFMA16(pa3, bC2, acc[3][2], 0, 0, 0);                       \
        acc[3][3] = MFMA16(pa3, bC3, acc[3][3], 0, 0, 0);                       \
        if ((itv) + 1 < BIT) {                                                  \
            bC0 = vbp[((itv) + 1) * 1024];       bC1 = vbp[((itv) + 1) * 1024 + 64];  \
            bC2 = vbp[((itv) + 1) * 1024 + 128]; bC3 = vbp[((itv) + 1) * 1024 + 192]; \
        }                                                                       \
    }

    for (int G = 0; G < NG; ++G) {
        const int it4 = G * 4;
        BODYM(Uc, 1, 0, it4 + 0)
        // after step0: pack halfB(G+1) [issued 2 steps ago]; issue halfA(G+2)
        if (G + 1 < NG) { PACK4(La, G + 1, 1) }
        if (G + 2 < NG) { ISSUE4(La, G + 2, 0) }
        BODYM(Uc, 2, 1, it4 + 1)
        // after step1: G+1 masks complete & fenced -> prefetch Un
        if (G + 1 < NG) Un = *(const u32x4*)&Ms[w * 16 + r15][it4 + 4];
        BODYM(Uc, 3, 0, it4 + 2)
        // after step2: pack halfA(G+2); issue halfB(G+2)
        if (G + 2 < NG) { PACK4(La, G + 2, 0) ISSUE4(La, G + 2, 1) }
        BODYM(Un, 0, 1, it4 + 3)
        Uc = Un;
    }
#undef BODYM
#undef EXPBLK
#undef ISSUE4
#undef PACK4

    sl += __shfl_xor(sl, 16);
    sl += __shfl_xor(sl, 32);
    if (g == 0) Sp[(size_t)p * N_NODES + prow] = sl;

    __bf16* apb = accB + ((size_t)p * N_NODES + rowbase) * DOUT;
#pragma unroll
    for (int m = 0; m < 4; ++m)
#pragma unroll
        for (int r = 0; r < 4; ++r) {
            bf16x4 t2;
#pragma unroll
            for (int n = 0; n < 4; ++n) t2[n] = (__bf16)acc[m][n][r];
            *(bf16x4*)&apb[(size_t)(m * 16 + g * 4 + r) * DOUT + w * 64 + r15 * 4] = t2;
        }
}

// ---------------------------------------------------------------------------
// C: combine bf16 partials (permuted layout), softmax denom, leaky-relu,
// L2-normalize, +bias. Wave per row; un-permute on store (r3 mapping).
template<int JS>
__global__ __launch_bounds__(256) void k_final(const __bf16* __restrict__ accB,
                                               const float* __restrict__ Sp,
                                               const float* __restrict__ bias,
                                               float* __restrict__ out) {
    int lane = threadIdx.x & 63, wv = threadIdx.x >> 6;
    int row = blockIdx.x * 4 + wv;
    float s = 0.f;
    f32x4 av = (f32x4){0.f, 0.f, 0.f, 0.f};
#pragma unroll
    for (int pp = 0; pp < JS; ++pp) {
        bf16x4 t = *(const bf16x4*)&accB[((size_t)pp * N_NODES + row) * DOUT + lane * 4];
#pragma unroll
        for (int j = 0; j < 4; ++j) av[j] += (float)t[j];
        s += Sp[(size_t)pp * N_NODES + row];
    }
    float inv = 1.0f / fmaxf(s, 1e-30f);
    f32x4 o;
#pragma unroll
    for (int j = 0; j < 4; ++j) {
        float x = av[j] * inv;
        o[j] = fmaxf(x, ALPHA * x);
    }
    float sq = o[0] * o[0] + o[1] * o[1] + o[2] * o[2] + o[3] * o[3];
#pragma unroll
    for (int m = 1; m < 64; m <<= 1) sq += __shfl_xor(sq, m);
    float innrm = 1.0f / fmaxf(sqrtf(sq), 1e-12f);
#pragma unroll
    for (int j = 0; j < 4; ++j) {
        int col = (lane >> 4) * 64 + j * 16 + (lane & 15);
        out[(size_t)row * DOUT + col] = o[j] * innrm + bias[col];
    }
}

// ---------------------------------------------------------------------------
extern "C" void kernel_launch(void* const* d_in, const int* in_sizes, int n_in,
                              void* d_out, int out_size, void* d_ws, size_t ws_size,
                              hipStream_t stream) {
    const float* node   = (const float*)d_in[0];
    const int*   adj    = (const int*)d_in[1];
    const float* weight = (const float*)d_in[2];
    const float* a      = (const float*)d_in[3];
    const float* bias   = (const float*)d_in[4];
    float* out = (float*)d_out;

    const size_t fixed  = 4522240;                 // wB 256K + vB 4M + Q/K 64K + kmax
    const size_t per_js = 32768 + (size_t)N_NODES * DOUT * 2;   // Sp + accB(bf16)
    int js = (ws_size >= fixed + 8 * per_js) ? 8 : 4;

    char* ws = (char*)d_ws;
    bf16x8*   wB      = (bf16x8*)(ws);
    bf16x8*   vB      = (bf16x8*)(ws + 262144);
    float*    Q       = (float*)(ws + 4456448);
    float*    K       = (float*)(ws + 4489216);
    unsigned* kmaxkey = (unsigned*)(ws + 4521984);
    float*    Sp      = (float*)(ws + fixed);
    __bf16*   accB    = (__bf16*)(ws + fixed + (size_t)js * 32768);

    k_repack_w<<<dim3(64),  dim3(256), 0, stream>>>(weight, wB, kmaxkey);
    k_gemm1f  <<<dim3(256), dim3(256), 0, stream>>>(node, wB, a, vB, Q, K, kmaxkey);
    if (js == 8) {
        k_attn<8><<<dim3(128 * 8), dim3(256), 0, stream>>>(adj, vB, Q, K, kmaxkey, accB, Sp);
        k_final<8><<<dim3(2048), dim3(256), 0, stream>>>(accB, Sp, bias, out);
    } else {
        k_attn<4><<<dim3(128 * 4), dim3(256), 0, stream>>>(adj, vB, Q, K, kmaxkey, accB, Sp);
        k_final<4><<<dim3(2048), dim3(256), 0, stream>>>(accB, Sp, bias, out);
    }
}

// Round 11
// 111.709 us; speedup vs baseline: 2.0422x; 2.0422x over previous
//
#include <hip/hip_runtime.h>
#include <hip/hip_bf16.h>

#define N_NODES 8192
#define DIN     512
#define DOUT    256
#define ALPHA   0.2f
#define LOG2E   1.4426950408889634f

typedef __bf16 bf16x8 __attribute__((ext_vector_type(8)));
typedef __bf16 bf16x4 __attribute__((ext_vector_type(4)));
typedef float  f32x4  __attribute__((ext_vector_type(4)));
typedef int    i32x4  __attribute__((ext_vector_type(4)));
typedef unsigned u32x4 __attribute__((ext_vector_type(4)));

#define MFMA16 __builtin_amdgcn_mfma_f32_16x16x32_bf16

// ---------------------------------------------------------------------------
// A0: repack weight f32 [512][256] -> wB bf16 fragment layout. Zeroes kmaxkey.
__global__ __launch_bounds__(256) void k_repack_w(const float* __restrict__ w,
                                                  bf16x8* __restrict__ wB,
                                                  unsigned* __restrict__ kmaxkey) {
    if (blockIdx.x == 0 && threadIdx.x == 0) *kmaxkey = 0u;
    int u = blockIdx.x * 256 + threadIdx.x;   // 16384 units
    int lane = u & 63, t = u >> 6;
    int nt = t & 15, kt = t >> 4;
    int k0 = kt * 32 + (lane >> 4) * 8;
    int col = nt * 16 + (lane & 15);
    bf16x8 r;
#pragma unroll
    for (int i = 0; i < 8; ++i) r[i] = (__bf16)w[(size_t)(k0 + i) * DOUT + col];
    wB[u] = r;
}

// ---------------------------------------------------------------------------
// A1 (fused): v = node @ weight in registers; emits vB fragments (LDS bounce),
// Q/K scalars, global K-max.
__global__ __launch_bounds__(256) void k_gemm1f(const float* __restrict__ node,
                                                const bf16x8* __restrict__ wB,
                                                const float* __restrict__ a,
                                                bf16x8* __restrict__ vBo,
                                                float* __restrict__ Q, float* __restrict__ K,
                                                unsigned* __restrict__ kmaxkey) {
    __shared__ __bf16 vsh[32][260];   // +4 pad
    __shared__ float qksh[32][2];
    int lane = threadIdx.x & 63, w = threadIdx.x >> 6;
    int r15 = lane & 15, g = lane >> 4;
    int nh = w & 1, rh = w >> 1;
    int rowbase = blockIdx.x * 32;
    int myrow = rowbase + rh * 16 + r15;
    const float* np = node + (size_t)myrow * DIN + g * 8;

    f32x4 acc[8];
#pragma unroll
    for (int j = 0; j < 8; ++j) acc[j] = (f32x4){0.f, 0.f, 0.f, 0.f};

    f32x4 c0 = *(const f32x4*)np;
    f32x4 c1 = *(const f32x4*)(np + 4);
    f32x4 c2 = *(const f32x4*)(np + 32);
    f32x4 c3 = *(const f32x4*)(np + 36);
    const bf16x8* wp = wB + (size_t)(nh * 8) * 64 + lane;
    bf16x8 fr0 = wp[0], fr1 = wp[64], fr2 = wp[128], fr3 = wp[192];
    bf16x8 fr4 = wp[256], fr5 = wp[320], fr6 = wp[384], fr7 = wp[448];

    for (int kt = 0; kt < 16; ++kt) {
        f32x4 u0 = c0, u1 = c1;
        c0 = c2; c1 = c3;
        if (kt + 2 < 16) {
            c2 = *(const f32x4*)(np + (kt + 2) * 32);
            c3 = *(const f32x4*)(np + (kt + 2) * 32 + 4);
        }
        bf16x8 f0 = fr0, f1 = fr1, f2 = fr2, f3 = fr3;
        bf16x8 f4 = fr4, f5 = fr5, f6 = fr6, f7 = fr7;
        if (kt + 1 < 16) {
            const bf16x8* wn = wB + ((size_t)(kt + 1) * 16 + nh * 8) * 64 + lane;
            fr0 = wn[0]; fr1 = wn[64]; fr2 = wn[128]; fr3 = wn[192];
            fr4 = wn[256]; fr5 = wn[320]; fr6 = wn[384]; fr7 = wn[448];
        }
        bf16x8 af;
#pragma unroll
        for (int i = 0; i < 4; ++i) { af[i] = (__bf16)u0[i]; af[i + 4] = (__bf16)u1[i]; }
        acc[0] = MFMA16(af, f0, acc[0], 0, 0, 0);
        acc[1] = MFMA16(af, f1, acc[1], 0, 0, 0);
        acc[2] = MFMA16(af, f2, acc[2], 0, 0, 0);
        acc[3] = MFMA16(af, f3, acc[3], 0, 0, 0);
        acc[4] = MFMA16(af, f4, acc[4], 0, 0, 0);
        acc[5] = MFMA16(af, f5, acc[5], 0, 0, 0);
        acc[6] = MFMA16(af, f6, acc[6], 0, 0, 0);
        acc[7] = MFMA16(af, f7, acc[7], 0, 0, 0);
    }

    float qp0 = 0.f, qp1 = 0.f, qp2 = 0.f, qp3 = 0.f;
    float kp0 = 0.f, kp1 = 0.f, kp2 = 0.f, kp3 = 0.f;
#pragma unroll
    for (int j = 0; j < 8; ++j) {
        int col = (nh * 8 + j) * 16 + r15;
        float a1 = a[col], a2 = a[DOUT + col];
        qp0 += acc[j][0] * a1; qp1 += acc[j][1] * a1;
        qp2 += acc[j][2] * a1; qp3 += acc[j][3] * a1;
        kp0 += acc[j][0] * a2; kp1 += acc[j][1] * a2;
        kp2 += acc[j][2] * a2; kp3 += acc[j][3] * a2;
    }
#pragma unroll
    for (int m = 1; m < 16; m <<= 1) {
        qp0 += __shfl_xor(qp0, m); qp1 += __shfl_xor(qp1, m);
        qp2 += __shfl_xor(qp2, m); qp3 += __shfl_xor(qp3, m);
        kp0 += __shfl_xor(kp0, m); kp1 += __shfl_xor(kp1, m);
        kp2 += __shfl_xor(kp2, m); kp3 += __shfl_xor(kp3, m);
    }

#pragma unroll
    for (int j = 0; j < 8; ++j)
#pragma unroll
        for (int r = 0; r < 4; ++r)
            vsh[rh * 16 + g * 4 + r][(nh * 8 + j) * 16 + r15] = (__bf16)acc[j][r];
    if (nh == 0 && r15 == 0) {
        int rl = rh * 16 + g * 4;
        qksh[rl + 0][0] = qp0; qksh[rl + 1][0] = qp1; qksh[rl + 2][0] = qp2; qksh[rl + 3][0] = qp3;
        qksh[rl + 0][1] = kp0; qksh[rl + 1][1] = kp1; qksh[rl + 2][1] = kp2; qksh[rl + 3][1] = kp3;
    }
    __syncthreads();
    if (nh == 1 && r15 == 0) {
        int rl = rh * 16 + g * 4;
        int rw = rowbase + rl;
        float q0 = qp0 + qksh[rl + 0][0], q1 = qp1 + qksh[rl + 1][0];
        float q2 = qp2 + qksh[rl + 2][0], q3 = qp3 + qksh[rl + 3][0];
        float k0 = kp0 + qksh[rl + 0][1], k1 = kp1 + qksh[rl + 1][1];
        float k2 = kp2 + qksh[rl + 2][1], k3 = kp3 + qksh[rl + 3][1];
        Q[rw + 0] = q0; Q[rw + 1] = q1; Q[rw + 2] = q2; Q[rw + 3] = q3;
        K[rw + 0] = k0; K[rw + 1] = k1; K[rw + 2] = k2; K[rw + 3] = k3;
        float km = fmaxf(fmaxf(k0, k1), fmaxf(k2, k3));
        unsigned bits = __float_as_uint(km);
        unsigned key = (bits & 0x80000000u) ? ~bits : (bits | 0x80000000u);
        atomicMax(kmaxkey, key);
    }
#pragma unroll
    for (int uu = 0; uu < 4; ++uu) {
        int nt = w * 4 + uu;
        bf16x8 t;
#pragma unroll
        for (int i = 0; i < 8; ++i) t[i] = vsh[g * 8 + i][nt * 16 + r15];
        vBo[((size_t)blockIdx.x * 16 + nt) * 64 + lane] = t;
    }
}

// ---------------------------------------------------------------------------
// B (round-11): the r10 REGISTER-DIET pipeline at the CORRECT bound.
// r10's (256,3) made hipcc cap arch VGPRs at 256/3=84 (its model: arch cap =
// 256/min_waves; AGPRs separate) -> massive spill (159 MB writes, 227us).
// At (256,2) the cap is 128 >= the diet's ~100-arch live set -> spill-free.
// Diet vs r3: (1) vB single-buffered, frags for step t+1 loaded at the TAIL
// of step t (consumed after the next barrier = full-step latency cover;
// 16 VGPR, was 32 dual-set); (2) adj ring = ONE 4-load chunk (16 VGPR, was
// 32) on a 2-step cadence (pack+reissue after step0 and step2; each chunk
// in flight 2 steps ~1700cy >> HBM 900cy). Un mask prefetch after step1
// (one barrier after its last contributing pack). Same pT exp-pipelined
// exchange as r3 (verified). Expect: VGPR 128, WRITE ~35 MB, no scratch.
template<int JS>
__global__ __launch_bounds__(256, 2) void k_attn(const int* __restrict__ adj,
                                                 const bf16x8* __restrict__ vBg,
                                                 const float* __restrict__ Q,
                                                 const float* __restrict__ K,
                                                 const unsigned* __restrict__ kmaxkey,
                                                 __bf16* __restrict__ accB,
                                                 float* __restrict__ Sp) {
    constexpr int JR   = N_NODES / JS;
    constexpr int BIT  = JR / 32;          // k-steps (32 for JS=8)
    constexpr int NG   = BIT / 4;          // 4-step groups
    constexpr int MSTR = BIT + 4;          // pad
    __shared__ float    Ks[JR];
    __shared__ unsigned Ms[64][MSTR];
    __shared__ bf16x8   pT[2][4][64];

    int bid = blockIdx.x;
    int rb = bid / JS, p = bid % JS;       // p == XCD id (grid % 8 == 0)
    int lane = threadIdx.x & 63, w = threadIdx.x >> 6;
    int r15 = lane & 15, g = lane >> 4;
    int rowbase = rb * 64;
    int prow = rowbase + w * 16 + r15;
    int j0 = p * JR;

    const int hrow = w * 2 + (lane >> 5);          // 0..7
    const int* abase = adj + (size_t)(rowbase + hrow) * N_NODES + j0 + (lane & 31) * 4;

    // chunk = 4 loads (rows (H*4+q)*8 + hrow, q=0..3) of group GG's 128-col span
#define ISSUE4(L, GG, H) { _Pragma("unroll")                                     \
    for (int q = 0; q < 4; ++q)                                                  \
        L[q] = *(const i32x4*)(abase + (size_t)(((H) * 4 + q) * 8) * N_NODES + (GG) * 128); }

#define PACK4(L, GG, H) { _Pragma("unroll") for (int q = 0; q < 4; ++q) {        \
    unsigned long long b0_ = __ballot(L[q][0] != 0);                             \
    unsigned long long b1_ = __ballot(L[q][1] != 0);                             \
    unsigned long long b2_ = __ballot(L[q][2] != 0);                             \
    unsigned long long b3_ = __ballot(L[q][3] != 0);                             \
    if ((lane & 31) == 0) {                                                      \
        int hi_ = lane >> 5;                                                     \
        u32x4 u_;                                                                \
        u_[0] = hi_ ? (unsigned)(b0_ >> 32) : (unsigned)b0_;                     \
        u_[1] = hi_ ? (unsigned)(b1_ >> 32) : (unsigned)b1_;                     \
        u_[2] = hi_ ? (unsigned)(b2_ >> 32) : (unsigned)b2_;                     \
        u_[3] = hi_ ? (unsigned)(b3_ >> 32) : (unsigned)b3_;                     \
        *(u32x4*)&Ms[((H) * 4 + q) * 8 + hrow][(GG) * 4] = u_;                   \
    } } }

    // ---- prologue: pack group0 (both halves) + group1 halfA; issue g1 halfB
    i32x4 La[4];
    ISSUE4(La, 0, 0)
    for (int s = threadIdx.x * 4; s < JR; s += 1024)
        *(f32x4*)&Ks[s] = *(const f32x4*)&K[j0 + s];
    PACK4(La, 0, 0)
    ISSUE4(La, 0, 1)

    float qi = Q[prow];
    unsigned kk = *kmaxkey;
    unsigned kb = (kk & 0x80000000u) ? (kk ^ 0x80000000u) : ~kk;
    float kmax = __uint_as_float(kb);
    float t0 = qi + kmax;
    float c2 = fmaxf(t0, ALPHA * t0) * LOG2E;
    float qiL = qi * LOG2E;
    float A1 = qiL - c2;
    float A2 = ALPHA * qiL - c2;

    PACK4(La, 0, 1)
    ISSUE4(La, 1, 0)

    const bf16x8* vbp = vBg + ((size_t)(p * BIT) * 16 + w * 4) * 64 + lane;

    f32x4 acc[4][4];
#pragma unroll
    for (int m = 0; m < 4; ++m)
#pragma unroll
        for (int n = 0; n < 4; ++n) acc[m][n] = (f32x4){0.f, 0.f, 0.f, 0.f};
    float sl = 0.f;

    PACK4(La, 1, 0)
    ISSUE4(La, 1, 1)       // in flight; packed at after-step0 of G=0

    // vB single-buffer: step-0 fragments
    bf16x8 bC0 = vbp[0], bC1 = vbp[64], bC2 = vbp[128], bC3 = vbp[192];

    // Ks + Ms(group0 + group1-halfA) visible; g1-halfB loads + bC in flight.
    asm volatile("s_waitcnt lgkmcnt(0)" ::: "memory");
    __builtin_amdgcn_s_barrier();
    asm volatile("" ::: "memory");

    u32x4 Uc = *(const u32x4*)&Ms[w * 16 + r15][0];
    u32x4 Un = Uc;

#define EXPBLK(WN4, SN, kstep)                                                  \
    {                                                                           \
        f32x4 q0 = *(const f32x4*)&Ks[(kstep) * 32 + g * 8];                    \
        f32x4 q1 = *(const f32x4*)&Ks[(kstep) * 32 + g * 8 + 4];                \
        unsigned bsh = (SN) * 8 + g * 2;                                        \
        unsigned m0 = (WN4)[0] >> bsh, m1 = (WN4)[1] >> bsh;                    \
        unsigned m2 = (WN4)[2] >> bsh, m3 = (WN4)[3] >> bsh;                    \
        _Pragma("unroll")                                                       \
        for (int i = 0; i < 8; ++i) {                                           \
            float kj = (i < 4) ? q0[i] : q1[i - 4];                             \
            float f1 = __builtin_fmaf(kj, LOG2E, A1);                           \
            float f2 = __builtin_fmaf(kj, ALPHA * LOG2E, A2);                   \
            float pv = __builtin_amdgcn_exp2f(fmaxf(f1, f2));                   \
            unsigned mm_ = (i & 3) == 0 ? m0 : ((i & 3) == 1 ? m1 : ((i & 3) == 2 ? m2 : m3)); \
            pv = (mm_ & (1u << (i >> 2))) ? pv : 0.f;                           \
            sl += pv;                                                           \
            afc[i] = (__bf16)pv;                                                \
        }                                                                       \
    }

    bf16x8 afc;
    EXPBLK(Uc, 0, 0)

    // step body: store af(t) -> barrier -> pa reads -> exp(t+1) -> 16 MFMA
    // with bC (loaded at tail of step t-1) -> tail-load bC for t+1.
#define BODYM(WN4, SN, BUF, itv)                                                \
    {                                                                           \
        pT[BUF][w][lane] = afc;                                                 \
        asm volatile("s_waitcnt lgkmcnt(0)" ::: "memory");                      \
        __builtin_amdgcn_s_barrier();                                           \
        asm volatile("" ::: "memory");                                         \
        bf16x8 pa0 = pT[BUF][0][lane], pa1 = pT[BUF][1][lane];                  \
        bf16x8 pa2 = pT[BUF][2][lane], pa3 = pT[BUF][3][lane];                  \
        if ((itv) + 1 < BIT) EXPBLK(WN4, SN, (itv) + 1)                         \
        acc[0][0] = MFMA16(pa0, bC0, acc[0][0], 0, 0, 0);                       \
        acc[0][1] = MFMA16(pa0, bC1, acc[0][1], 0, 0, 0);                       \
        acc[0][2] = MFMA16(pa0, bC2, acc[0][2], 0, 0, 0);                       \
        acc[0][3] = MFMA16(pa0, bC3, acc[0][3], 0, 0, 0);                       \
        acc[1][0] = MFMA16(pa1, bC0, acc[1][0], 0, 0, 0);                       \
        acc[1][1] = MFMA16(pa1, bC1, acc[1][1], 0, 0, 0);                       \
        acc[1][2] = MFMA16(pa1, bC2, acc[1][2], 0, 0, 0);                       \
        acc[1][3] = MFMA16(pa1, bC3, acc[1][3], 0, 0, 0);                       \
        acc[2][0] = MFMA16(pa2, bC0, acc[2][0], 0, 0, 0);                       \
        acc[2][1] = MFMA16(pa2, bC1, acc[2][1], 0, 0, 0);                       \
        acc[2][2] = MFMA16(pa2, bC2, acc[2][2], 0, 0, 0);                       \
        acc[2][3] = MFMA16(pa2, bC3, acc[2][3], 0, 0, 0);                       \
        acc[3][0] = MFMA16(pa3, bC0, acc[3][0], 0, 0, 0);                       \
        acc[3][1] = MFMA16(pa3, bC1, acc[3][1], 0, 0, 0);                       \
        acc[3][2] = MFMA16(pa3, bC2, acc[3][2], 0, 0, 0);                       \
        acc[3][3] = MFMA16(pa3, bC3, acc[3][3], 0, 0, 0);                       \
        if ((itv) + 1 < BIT) {                                                  \
            bC0 = vbp[((itv) + 1) * 1024];       bC1 = vbp[((itv) + 1) * 1024 + 64];  \
            bC2 = vbp[((itv) + 1) * 1024 + 128]; bC3 = vbp[((itv) + 1) * 1024 + 192]; \
        }                                                                       \
    }

    for (int G = 0; G < NG; ++G) {
        const int it4 = G * 4;
        BODYM(Uc, 1, 0, it4 + 0)
        // after step0: pack halfB(G+1) [issued 2 steps ago]; issue halfA(G+2)
        if (G + 1 < NG) { PACK4(La, G + 1, 1) }
        if (G + 2 < NG) { ISSUE4(La, G + 2, 0) }
        BODYM(Uc, 2, 1, it4 + 1)
        // after step1: G+1 masks complete & fenced -> prefetch Un
        if (G + 1 < NG) Un = *(const u32x4*)&Ms[w * 16 + r15][it4 + 4];
        BODYM(Uc, 3, 0, it4 + 2)
        // after step2: pack halfA(G+2); issue halfB(G+2)
        if (G + 2 < NG) { PACK4(La, G + 2, 0) ISSUE4(La, G + 2, 1) }
        BODYM(Un, 0, 1, it4 + 3)
        Uc = Un;
    }
#undef BODYM
#undef EXPBLK
#undef ISSUE4
#undef PACK4

    sl += __shfl_xor(sl, 16);
    sl += __shfl_xor(sl, 32);
    if (g == 0) Sp[(size_t)p * N_NODES + prow] = sl;

    __bf16* apb = accB + ((size_t)p * N_NODES + rowbase) * DOUT;
#pragma unroll
    for (int m = 0; m < 4; ++m)
#pragma unroll
        for (int r = 0; r < 4; ++r) {
            bf16x4 t2;
#pragma unroll
            for (int n = 0; n < 4; ++n) t2[n] = (__bf16)acc[m][n][r];
            *(bf16x4*)&apb[(size_t)(m * 16 + g * 4 + r) * DOUT + w * 64 + r15 * 4] = t2;
        }
}

// ---------------------------------------------------------------------------
// C: combine bf16 partials (permuted layout), softmax denom, leaky-relu,
// L2-normalize, +bias. Wave per row; un-permute on store (r3 mapping).
template<int JS>
__global__ __launch_bounds__(256) void k_final(const __bf16* __restrict__ accB,
                                               const float* __restrict__ Sp,
                                               const float* __restrict__ bias,
                                               float* __restrict__ out) {
    int lane = threadIdx.x & 63, wv = threadIdx.x >> 6;
    int row = blockIdx.x * 4 + wv;
    float s = 0.f;
    f32x4 av = (f32x4){0.f, 0.f, 0.f, 0.f};
#pragma unroll
    for (int pp = 0; pp < JS; ++pp) {
        bf16x4 t = *(const bf16x4*)&accB[((size_t)pp * N_NODES + row) * DOUT + lane * 4];
#pragma unroll
        for (int j = 0; j < 4; ++j) av[j] += (float)t[j];
        s += Sp[(size_t)pp * N_NODES + row];
    }
    float inv = 1.0f / fmaxf(s, 1e-30f);
    f32x4 o;
#pragma unroll
    for (int j = 0; j < 4; ++j) {
        float x = av[j] * inv;
        o[j] = fmaxf(x, ALPHA * x);
    }
    float sq = o[0] * o[0] + o[1] * o[1] + o[2] * o[2] + o[3] * o[3];
#pragma unroll
    for (int m = 1; m < 64; m <<= 1) sq += __shfl_xor(sq, m);
    float innrm = 1.0f / fmaxf(sqrtf(sq), 1e-12f);
#pragma unroll
    for (int j = 0; j < 4; ++j) {
        int col = (lane >> 4) * 64 + j * 16 + (lane & 15);
        out[(size_t)row * DOUT + col] = o[j] * innrm + bias[col];
    }
}

// ---------------------------------------------------------------------------
extern "C" void kernel_launch(void* const* d_in, const int* in_sizes, int n_in,
                              void* d_out, int out_size, void* d_ws, size_t ws_size,
                              hipStream_t stream) {
    const float* node   = (const float*)d_in[0];
    const int*   adj    = (const int*)d_in[1];
    const float* weight = (const float*)d_in[2];
    const float* a      = (const float*)d_in[3];
    const float* bias   = (const float*)d_in[4];
    float* out = (float*)d_out;

    const size_t fixed  = 4522240;                 // wB 256K + vB 4M + Q/K 64K + kmax
    const size_t per_js = 32768 + (size_t)N_NODES * DOUT * 2;   // Sp + accB(bf16)
    int js = (ws_size >= fixed + 8 * per_js) ? 8 : 4;

    char* ws = (char*)d_ws;
    bf16x8*   wB      = (bf16x8*)(ws);
    bf16x8*   vB      = (bf16x8*)(ws + 262144);
    float*    Q       = (float*)(ws + 4456448);
    float*    K       = (float*)(ws + 4489216);
    unsigned* kmaxkey = (unsigned*)(ws + 4521984);
    float*    Sp      = (float*)(ws + fixed);
    __bf16*   accB    = (__bf16*)(ws + fixed + (size_t)js * 32768);

    k_repack_w<<<dim3(64),  dim3(256), 0, stream>>>(weight, wB, kmaxkey);
    k_gemm1f  <<<dim3(256), dim3(256), 0, stream>>>(node, wB, a, vB, Q, K, kmaxkey);
    if (js == 8) {
        k_attn<8><<<dim3(128 * 8), dim3(256), 0, stream>>>(adj, vB, Q, K, kmaxkey, accB, Sp);
        k_final<8><<<dim3(2048), dim3(256), 0, stream>>>(accB, Sp, bias, out);
    } else {
        k_attn<4><<<dim3(128 * 4), dim3(256), 0, stream>>>(adj, vB, Q, K, kmaxkey, accB, Sp);
        k_final<4><<<dim3(2048), dim3(256), 0, stream>>>(accB, Sp, bias, out);
    }
}